// Round 15
// baseline (537.923 us; speedup 1.0000x reference)
//
#include <hip/hip_runtime.h>
#include <hip/hip_fp16.h>

typedef __attribute__((ext_vector_type(8))) short short8;
typedef __attribute__((ext_vector_type(8))) unsigned short u16x8;
typedef __attribute__((ext_vector_type(4))) float f32x4;

#define S_LEN 2048
#define BATCH 4
#define DM 1024
#define DI 2048
#define DS 64
#define DTR 64
#define XPW 192   // dt_rank + 2*d_state
#define NCH 16    // scan chunks
#define CLEN 128  // t per chunk

typedef const __attribute__((address_space(4))) unsigned* cu_as4;

__device__ __forceinline__ unsigned short f2bf(float f){
  unsigned u = __builtin_bit_cast(unsigned, f);
  u += 0x7fffu + ((u >> 16) & 1u);
  return (unsigned short)(u >> 16);
}
__device__ __forceinline__ float bf2f(unsigned short h){
  unsigned u = ((unsigned)h) << 16;
  return __builtin_bit_cast(float, u);
}
__device__ __forceinline__ void gload16(const void* g, void* l){
  __builtin_amdgcn_global_load_lds((const __attribute__((address_space(1))) void*)g,
                                   (__attribute__((address_space(3))) void*)l, 16, 0, 0);
}
__device__ __forceinline__ float siluf_(float v){ return v / (1.f + __expf(-v)); }

// ---------------- fused f32 -> bf16 convert (4 segments) ----------------
__global__ __launch_bounds__(256) void cvt_all_k(const float* __restrict__ i0, unsigned short* __restrict__ o0,
                                                 const float* __restrict__ i1, unsigned short* __restrict__ o1,
                                                 const float* __restrict__ i2, unsigned short* __restrict__ o2,
                                                 const float* __restrict__ i3, unsigned short* __restrict__ o3)
{
  int bid = blockIdx.x;
  const float* in; unsigned short* out; int base;
  if (bid < 8192)       { in = i0; out = o0; base = bid; }
  else if (bid < 12288) { in = i1; out = o1; base = bid - 8192; }
  else if (bid < 12672) { in = i2; out = o2; base = bid - 12288; }
  else                  { in = i3; out = o3; base = bid - 12672; }
  int i = (base * 256 + threadIdx.x) * 4;
  float4 v = *(const float4*)(in + i);
  ushort4 o;
  o.x = f2bf(v.x); o.y = f2bf(v.y); o.z = f2bf(v.z); o.w = f2bf(v.w);
  *(ushort4*)(out + i) = o;
}

// ===== gemm_in: 128x128 tile, 4-deep LDS ring, counted vmcnt, raw barriers ====
// C = A[8192,1024] * B[4096,1024]^T + bias; cols<2048 -> xib bf16, else silu->grm.
// LDS permutation: phys_block(row,seg) = (row>>3)*32 + seg*8 + (row&7)
// (applied on the global SOURCE at staging and on ds_read offsets; linear dest.)
__global__ __launch_bounds__(256)
void gemm_in8_k(const unsigned short* __restrict__ A, const unsigned short* __restrict__ B,
                const float* __restrict__ bias,
                unsigned short* __restrict__ xib, unsigned short* __restrict__ grm)
{
  __shared__ unsigned short As[4][4096];   // 4 x 8KB
  __shared__ unsigned short Bs[4][4096];   // 4 x 8KB
  const int tid  = threadIdx.x;
  const int lane = tid & 63;
  const int wid  = tid >> 6;
  int flat = blockIdx.y * 64 + blockIdx.x;
  int swz = (flat & 7) * 256 + (flat >> 3);       // XCD-contiguous (2048%8==0)
  const int bm = swz & 63, bn = swz >> 6;

  // staging: thread handles phys blocks {tid, 256+tid} for A and for B
  const unsigned short* srcA[2]; const unsigned short* srcB[2];
  int ldso[2];
#pragma unroll
  for (int q = 0; q < 2; ++q) {
    int s   = q * 256 + tid;
    int row = ((s >> 5) << 3) | (s & 7);
    int seg = (s >> 3) & 3;
    srcA[q] = A + (size_t)(bm * 128 + row) * 1024 + seg * 8;
    srcB[q] = B + (size_t)(bn * 128 + row) * 1024 + seg * 8;
    ldso[q] = s * 8;
  }
  // fragment read offsets (physical, ushort units)
  const int fr = lane & 15, fq = lane >> 4;
  const int wm = (wid >> 1) * 64, wn = (wid & 1) * 64;
  int aoff[4], boff[4];
#pragma unroll
  for (int f = 0; f < 4; ++f) {
    aoff[f] = ((((wm >> 3) + 2 * f + (fr >> 3)) * 32) + fq * 8 + (fr & 7)) * 8;
    boff[f] = ((((wn >> 3) + 2 * f + (fr >> 3)) * 32) + fq * 8 + (fr & 7)) * 8;
  }

#define GLA(t,q) gload16(srcA[q] + (size_t)(t) * 32, &As[(t) & 3][ldso[q]])
#define GLB(t,q) gload16(srcB[q] + (size_t)(t) * 32, &Bs[(t) & 3][ldso[q]])
  // prologue: stage tiles 0,1,2 (tile-major issue order for vmcnt counting)
#pragma unroll
  for (int t = 0; t < 3; ++t) { GLA(t,0); GLA(t,1); GLB(t,0); GLB(t,1); }
  asm volatile("s_waitcnt vmcnt(8)" ::: "memory");   // tile 0 landed
  __builtin_amdgcn_sched_barrier(0);
  __builtin_amdgcn_s_barrier();
  __builtin_amdgcn_sched_barrier(0);

  f32x4 acc[4][4] = {};
  for (int kt = 0; kt < 32; ++kt) {
    const int buf = kt & 3;
    // ---- phase 0: stage A of kt+3, read B + A(0,1), 8 MFMA
    if (kt + 3 < 32) { GLA(kt + 3, 0); GLA(kt + 3, 1); }
    short8 bv[4];
#pragma unroll
    for (int j = 0; j < 4; ++j) bv[j] = *(const short8*)&Bs[buf][boff[j]];
    short8 av0 = *(const short8*)&As[buf][aoff[0]];
    short8 av1 = *(const short8*)&As[buf][aoff[1]];
    __builtin_amdgcn_s_setprio(1);
#pragma unroll
    for (int j = 0; j < 4; ++j)
      acc[0][j] = __builtin_amdgcn_mfma_f32_16x16x32_bf16(av0, bv[j], acc[0][j], 0, 0, 0);
#pragma unroll
    for (int j = 0; j < 4; ++j)
      acc[1][j] = __builtin_amdgcn_mfma_f32_16x16x32_bf16(av1, bv[j], acc[1][j], 0, 0, 0);
    __builtin_amdgcn_s_setprio(0);
    // ---- phase 1: stage B of kt+3, read A(2,3), 8 MFMA
    if (kt + 3 < 32) { GLB(kt + 3, 0); GLB(kt + 3, 1); }
    short8 av2 = *(const short8*)&As[buf][aoff[2]];
    short8 av3 = *(const short8*)&As[buf][aoff[3]];
    __builtin_amdgcn_s_setprio(1);
#pragma unroll
    for (int j = 0; j < 4; ++j)
      acc[2][j] = __builtin_amdgcn_mfma_f32_16x16x32_bf16(av2, bv[j], acc[2][j], 0, 0, 0);
#pragma unroll
    for (int j = 0; j < 4; ++j)
      acc[3][j] = __builtin_amdgcn_mfma_f32_16x16x32_bf16(av3, bv[j], acc[3][j], 0, 0, 0);
    __builtin_amdgcn_s_setprio(0);
    // ---- tile boundary: counted wait (never drain mid-loop) + raw barrier
    if (kt == 31) break;
    if (kt <= 28)      asm volatile("s_waitcnt vmcnt(8)" ::: "memory");
    else if (kt == 29) asm volatile("s_waitcnt vmcnt(4)" ::: "memory");
    else               asm volatile("s_waitcnt vmcnt(0)" ::: "memory");
    __builtin_amdgcn_sched_barrier(0);
    __builtin_amdgcn_s_barrier();
    __builtin_amdgcn_sched_barrier(0);
  }
#undef GLA
#undef GLB

  // epilogue: identical mapping to prior EPI2
#pragma unroll
  for (int i = 0; i < 4; i++) {
#pragma unroll
    for (int j = 0; j < 4; j++) {
      int gc = bn * 128 + wn + j * 16 + fr;
      float bb = bias[gc];
#pragma unroll
      for (int e = 0; e < 4; e++) {
        int gr = bm * 128 + wm + i * 16 + fq * 4 + e;
        float v = acc[i][j][e] + bb;
        if (gc < 2048) xib[(size_t)gr * DI + gc] = f2bf(v);
        else           grm[(size_t)gr * DI + (gc - 2048)] = f2bf(siluf_(v));
      }
    }
  }
}

// ---------------- bf16 MFMA GEMM (old structure) for dt / xp paths -----------
template<int EPI>
__global__ __launch_bounds__(256)
void gemm_bt(const unsigned short* __restrict__ A, const unsigned short* __restrict__ B,
             const float* __restrict__ bias,
             int N, int K, int lda, int ldb,
             void* __restrict__ vp0, void* __restrict__ vp1,
             const void* __restrict__ vp2, const void* __restrict__ vp3,
             int nsilu, float* __restrict__ sdt)
{
  __shared__ unsigned short As[128 * 32];
  __shared__ unsigned short Bs[128 * 32];
  const int tid  = threadIdx.x;
  const int lane = tid & 63;
  const int wid  = tid >> 6;
  int bm = blockIdx.x, bn = blockIdx.y;
  int k_lo = 0, k_hi = K;
  if constexpr (EPI == 3) { k_lo = blockIdx.z * 512; k_hi = k_lo + 512; }
  const int r0 = tid >> 2;           // 0..63
  const int c0 = (tid & 3) * 8;      // 0,8,16,24
  int brow0 = bn * 128 + r0;        if (brow0 > N - 1) brow0 = N - 1;
  int brow1 = bn * 128 + 64 + r0;   if (brow1 > N - 1) brow1 = N - 1;
  const unsigned short* pa0 = A + (size_t)(bm * 128 + r0) * lda + c0;
  const unsigned short* pa1 = A + (size_t)(bm * 128 + 64 + r0) * lda + c0;
  const unsigned short* pb0 = B + (size_t)brow0 * ldb + c0;
  const unsigned short* pb1 = B + (size_t)brow1 * ldb + c0;
  f32x4 acc[4][4] = {};
  const int fr = lane & 15, fq = lane >> 4;
  const int wm = (wid >> 1) * 64, wn = (wid & 1) * 64;
  const int aoff0 = (wm + fr) * 32 + fq * 8;
  const int boff0 = (wn + fr) * 32 + fq * 8;
  for (int k0 = k_lo; k0 < k_hi; k0 += 32) {
    __syncthreads();
    gload16(pa0 + k0, &As[tid * 8]);
    gload16(pa1 + k0, &As[2048 + tid * 8]);
    gload16(pb0 + k0, &Bs[tid * 8]);
    gload16(pb1 + k0, &Bs[2048 + tid * 8]);
    __syncthreads();
    short8 av[4], bv[4];
#pragma unroll
    for (int i = 0; i < 4; i++) av[i] = *(const short8*)&As[aoff0 + i * 16 * 32];
#pragma unroll
    for (int i = 0; i < 4; i++) bv[i] = *(const short8*)&Bs[boff0 + i * 16 * 32];
#pragma unroll
    for (int i = 0; i < 4; i++)
#pragma unroll
      for (int j = 0; j < 4; j++)
        acc[i][j] = __builtin_amdgcn_mfma_f32_16x16x32_bf16(av[i], bv[j], acc[i][j], 0, 0, 0);
  }

  if constexpr (EPI == 3) {
    float* xpp = (float*)vp0;     // [4][8192][256] partials
    const size_t kb = (size_t)blockIdx.z * 8192 * 256;
#pragma unroll
    for (int i = 0; i < 4; i++) {
#pragma unroll
      for (int j = 0; j < 4; j++) {
        int gc = bn * 128 + wn + j * 16 + fr;   // 0..255
#pragma unroll
        for (int e = 0; e < 4; e++) {
          int gr = bm * 128 + wm + i * 16 + fq * 4 + e;
          xpp[kb + (size_t)gr * 256 + gc] = acc[i][j][e];
        }
      }
    }
  } else {
    // EPI == 1: dt path; LDS-stage dt bf16, then fully coalesced global epilogue
    unsigned* dtH = (unsigned*)vp0;                    // [4][256][2048][4] u32 (bf16 pairs)
    unsigned* dxg = (unsigned*)vp1;                    // [4][256][2048][8] u32
    const unsigned short* xcb = (const unsigned short*)vp2;
    const unsigned short* grm = (const unsigned short*)vp3;
#pragma unroll
    for (int j = 0; j < 4; j++) {
      int gc = bn * 128 + wn + j * 16 + fr;
      float bb2 = 2.f * bias[gc];
#pragma unroll
      for (int i = 0; i < 4; i++)
#pragma unroll
        for (int e = 0; e < 4; e++) {
          float v = acc[i][j][e] + bb2;
          acc[i][j][e] = fmaxf(v, 0.f) + log1pf(__expf(-fabsf(v)));
        }
    }
    __shared__ unsigned short hbuf[256 * 36];          // 18 KiB, dt bf16 (row = e*64+dl)
    const int myc = wn >> 6;
    const int tbase = wm / 4;
    const int chk = bm >> 2;
    for (int cc = 0; cc < 2; ++cc) {
      __syncthreads();
      if (myc == cc) {
#pragma unroll
        for (int i = 0; i < 4; i++)
#pragma unroll
          for (int j = 0; j < 4; j++) {
            int dl = j * 16 + fr;
            int t_ = tbase + i * 4 + fq;
#pragma unroll
            for (int e = 0; e < 4; e++)
              hbuf[(e * 64 + dl) * 36 + t_] = f2bf(acc[i][j][e]);
          }
      }
      __syncthreads();
#pragma unroll
      for (int k = 0; k < 4; ++k) {                    // dtH
        int gidx = tid + k * 256;
        int t   = gidx & 31;
        int gl8 = (gidx >> 5) & 7;
        int e   = gidx >> 8;
        int R   = e * 64 + gl8 * 8;
        uint4 o;
        o.x = (unsigned)hbuf[(R+0)*36 + t] | ((unsigned)hbuf[(R+1)*36 + t] << 16);
        o.y = (unsigned)hbuf[(R+2)*36 + t] | ((unsigned)hbuf[(R+3)*36 + t] << 16);
        o.z = (unsigned)hbuf[(R+4)*36 + t] | ((unsigned)hbuf[(R+5)*36 + t] << 16);
        o.w = (unsigned)hbuf[(R+6)*36 + t] | ((unsigned)hbuf[(R+7)*36 + t] << 16);
        size_t G = (size_t)(bn * 16 + cc * 8 + gl8);
        *(uint4*)&dtH[(((size_t)e * 256 + G) * 2048 + bm * 32 + t) * 4] = o;
      }
#pragma unroll
      for (int k = 0; k < 4; ++k) {                    // dxg
        int gidx = tid + k * 256;
        int t   = gidx & 31;
        int gl8 = (gidx >> 5) & 7;
        int e   = gidx >> 8;
        int gr  = (bm * 32 + t) * 4 + e;
        int col = bn * 128 + cc * 64 + gl8 * 8;
        u16x8 xv = *(const u16x8*)&xcb[(size_t)gr * DI + col];
        u16x8 gv = *(const u16x8*)&grm[(size_t)gr * DI + col];
        int R = e * 64 + gl8 * 8;
        unsigned ow[8];
#pragma unroll
        for (int u = 0; u < 8; ++u) {
          float dt = bf2f(hbuf[(R + u) * 36 + t]);
          float dtx = dt * bf2f((unsigned short)xv[u]);
          ow[u] = ((unsigned)f2bf(dtx) << 16) | (unsigned)(unsigned short)gv[u];
        }
        size_t G = (size_t)(bn * 16 + cc * 8 + gl8);
        unsigned* dst = &dxg[(((size_t)e * 256 + G) * 2048 + bm * 32 + t) * 8];
        uint4 o0, o1;
        o0.x = ow[0]; o0.y = ow[1]; o0.z = ow[2]; o0.w = ow[3];
        o1.x = ow[4]; o1.y = ow[5]; o1.z = ow[6]; o1.w = ow[7];
        *(uint4*)dst = o0;
        *(uint4*)(dst + 4) = o1;
      }
      {
        int e  = tid >> 6;
        int dl = tid & 63;
        float s = 0.f;
#pragma unroll
        for (int t = 0; t < 32; ++t)
          s += bf2f(hbuf[(e * 64 + dl) * 36 + t]);
        int g8 = bn * 16 + cc * 8 + (dl >> 3);
        atomicAdd(&sdt[(((size_t)e * NCH + chk) * 256 + g8) * 8 + (dl & 7)], s);
      }
    }
  }
}

// ------- xp split-K reduce: sum 4 partials + bias -> xpb bf16 + bcI float2 ----
__global__ __launch_bounds__(192) void xpred_k(const float* __restrict__ xpp,
                                               const float* __restrict__ bias,
                                               unsigned short* __restrict__ xpb,
                                               float* __restrict__ bcI)
{
  const int gr = blockIdx.x;         // 0..8191
  const int gc = threadIdx.x;        // 0..191
  const size_t o = (size_t)gr * 256 + gc;
  float v = xpp[o] + xpp[o + 2097152] + xpp[o + 2 * 2097152] + xpp[o + 3 * 2097152] + bias[gc];
  xpb[(size_t)gr * XPW + gc] = f2bf(v);
  if (gc >= 64 && gc < 128)      bcI[((size_t)gr * 64 + gc - 64) * 2 + 0] = v;
  else if (gc >= 128)            bcI[((size_t)gr * 64 + gc - 128) * 2 + 1] = v;
}

// ------ fused causal depthwise conv (K=4) + silu + D-term partial reduce ------
__global__ __launch_bounds__(256) void convsxg_k(const unsigned short* __restrict__ xib,
                                                 const unsigned short* __restrict__ grm,
                                                 const float* __restrict__ cw,
                                                 const float* __restrict__ cb,
                                                 unsigned short* __restrict__ xcb,
                                                 float* __restrict__ sxg)
{
  const int d4 = blockIdx.x * 1024 + threadIdx.x * 4;
  const int b  = blockIdx.y;
  const int t0 = blockIdx.z * 16;
  float4 cwv[4]; float cbv[4];
#pragma unroll
  for (int j = 0; j < 4; ++j) { cwv[j] = *(const float4*)&cw[(d4 + j) * 4]; cbv[j] = cb[d4 + j]; }
  ushort4 z4; z4.x = z4.y = z4.z = z4.w = 0;
  ushort4 xm1 = (t0 >= 1) ? *(const ushort4*)&xib[((size_t)((t0 - 1) * 4 + b)) * DI + d4] : z4;
  ushort4 xm2 = (t0 >= 2) ? *(const ushort4*)&xib[((size_t)((t0 - 2) * 4 + b)) * DI + d4] : z4;
  ushort4 xm3 = (t0 >= 3) ? *(const ushort4*)&xib[((size_t)((t0 - 3) * 4 + b)) * DI + d4] : z4;
  float sa[4] = {0.f, 0.f, 0.f, 0.f};
  for (int tt = 0; tt < 16; ++tt) {
    const int t = t0 + tt;
    const size_t row = ((size_t)(t * 4 + b)) * DI + d4;
    ushort4 x0 = *(const ushort4*)&xib[row];
    ushort4 gv = *(const ushort4*)&grm[row];
    unsigned short xr[4] = {x0.x, x0.y, x0.z, x0.w};
    unsigned short r1[4] = {xm1.x, xm1.y, xm1.z, xm1.w};
    unsigned short r2[4] = {xm2.x, xm2.y, xm2.z, xm2.w};
    unsigned short r3[4] = {xm3.x, xm3.y, xm3.z, xm3.w};
    unsigned short gg[4] = {gv.x, gv.y, gv.z, gv.w};
    unsigned short ov[4];
#pragma unroll
    for (int j = 0; j < 4; ++j) {
      float s = cbv[j];
      s = fmaf(cwv[j].w, bf2f(xr[j]), s);
      s = fmaf(cwv[j].z, bf2f(r1[j]), s);
      s = fmaf(cwv[j].y, bf2f(r2[j]), s);
      s = fmaf(cwv[j].x, bf2f(r3[j]), s);
      ov[j] = f2bf(siluf_(s));
      sa[j] = fmaf(bf2f(ov[j]), bf2f(gg[j]), sa[j]);
    }
    ushort4 o; o.x = ov[0]; o.y = ov[1]; o.z = ov[2]; o.w = ov[3];
    *(ushort4*)&xcb[row] = o;
    xm3 = xm2; xm2 = xm1; xm1 = x0;
  }
#pragma unroll
  for (int j = 0; j < 4; ++j) atomicAdd(&sxg[b * DI + d4 + j], sa[j]);
}

// ------- chunk-parallel scan: wave = (b, chunk, 8-ch group), lane = n ---------
__global__ __launch_bounds__(256) void scan_k(const unsigned* __restrict__ dtHg,
                                              const unsigned* __restrict__ dxgg,
                                              const float* __restrict__ bcI,
                                              const float* __restrict__ A_log,
                                              float* __restrict__ Pb,
                                              float* __restrict__ Fb,
                                              float* __restrict__ accp)
{
  const int tid  = threadIdx.x;
  const int lane = tid & 63;
  const int gw = __builtin_amdgcn_readfirstlane(blockIdx.x * 4 + (tid >> 6));  // 0..16383
  const int b  = gw >> 12;
  const int c  = (gw >> 8) & 15;
  const int g  = gw & 255;
  const int d0 = g * 8;
  const float LOG2E = 1.4426950408889634f;
  float a2[8], st[8], Dr[8], Fr[8], acc[8];
#pragma unroll
  for (int j = 0; j < 8; ++j) {
    a2[j] = -__expf(A_log[(size_t)(d0 + j) * DS + lane]) * LOG2E;
    st[j] = 0.f; Dr[j] = 1.f; Fr[j] = 0.f; acc[j] = 0.f;
  }
  cu_as4 pdt = (cu_as4)(unsigned long long)(dtHg + (((size_t)(b * 256 + g)) * S_LEN + c * CLEN) * 4);
  cu_as4 pdx = (cu_as4)(unsigned long long)(dxgg + (((size_t)(b * 256 + g)) * S_LEN + c * CLEN) * 8);
  const float* pbc = bcI + (((size_t)(c * CLEN) * 4 + b) * 64 + lane) * 2;
#pragma unroll 4
  for (int t = 0; t < CLEN; ++t) {
    unsigned dw0 = pdt[t * 4 + 0], dw1 = pdt[t * 4 + 1];
    unsigned dw2 = pdt[t * 4 + 2], dw3 = pdt[t * 4 + 3];
    unsigned xs[8];
#pragma unroll
    for (int j = 0; j < 8; ++j) xs[j] = pdx[t * 8 + j];
    float2 bc = *(const float2*)(pbc + (size_t)t * 512);
    float dts[8];
    dts[0] = __builtin_bit_cast(float, dw0 << 16);
    dts[1] = __builtin_bit_cast(float, dw0 & 0xffff0000u);
    dts[2] = __builtin_bit_cast(float, dw1 << 16);
    dts[3] = __builtin_bit_cast(float, dw1 & 0xffff0000u);
    dts[4] = __builtin_bit_cast(float, dw2 << 16);
    dts[5] = __builtin_bit_cast(float, dw2 & 0xffff0000u);
    dts[6] = __builtin_bit_cast(float, dw3 << 16);
    dts[7] = __builtin_bit_cast(float, dw3 & 0xffff0000u);
#pragma unroll
    for (int j = 0; j < 8; ++j) {
      float dxs = __builtin_bit_cast(float, xs[j] & 0xffff0000u);
      float gsv = __builtin_bit_cast(float, xs[j] << 16);
      float dA = __builtin_amdgcn_exp2f(dts[j] * a2[j]);
      st[j] = fmaf(st[j], dA, dxs * bc.x);
      Dr[j] *= dA;
      float w = gsv * bc.y;
      acc[j] = fmaf(st[j], w, acc[j]);
      Fr[j] = fmaf(Dr[j], w, Fr[j]);
    }
  }
  const size_t sb = (((size_t)((b * NCH + c) * 256 + g)) * 8) * 64 + lane;
#pragma unroll
  for (int j = 0; j < 8; ++j) {
    Pb[sb + j * 64] = st[j];
    Fb[sb + j * 64] = Fr[j];
  }
#pragma unroll
  for (int j = 0; j < 8; ++j)
#pragma unroll
    for (int m = 32; m; m >>= 1) acc[j] += __shfl_xor(acc[j], m, 64);
  if (lane == 0) {
#pragma unroll
    for (int j = 0; j < 8; ++j)
      accp[(b * NCH + c) * DI + d0 + j] = acc[j];
  }
}

// ------- chunk chain fixup: wave = (b, 8-ch group), serial over 16 chunks -----
__global__ __launch_bounds__(256) void fixup_k(const float* __restrict__ Pb,
                                               const float* __restrict__ Fb,
                                               const float* __restrict__ sdt,
                                               const float* __restrict__ accp,
                                               const float* __restrict__ A_log,
                                               const float* __restrict__ state_in,
                                               float* __restrict__ accbuf,
                                               float* __restrict__ state_out)
{
  const int tid  = threadIdx.x;
  const int lane = tid & 63;
  const int gw = blockIdx.x * 4 + (tid >> 6);   // 0..1023
  const int b  = gw >> 8;
  const int g  = gw & 255;
  const int d0 = g * 8;
  const float LOG2E = 1.4426950408889634f;
  float a2[8], S[8], v[8];
#pragma unroll
  for (int j = 0; j < 8; ++j) {
    a2[j] = -__expf(A_log[(size_t)(d0 + j) * DS + lane]) * LOG2E;
    S[j] = state_in[((size_t)(b * DI + d0 + j)) * DS + lane];
    v[j] = 0.f;
  }
#pragma unroll
  for (int c = 0; c < NCH; ++c) {
    const size_t sb = (((size_t)((b * NCH + c) * 256 + g)) * 8) * 64 + lane;
    const size_t se = (((size_t)(b * NCH + c)) * 256 + g) * 8;
#pragma unroll
    for (int j = 0; j < 8; ++j) {
      float P = Pb[sb + j * 64], F = Fb[sb + j * 64];
      float E = __builtin_amdgcn_exp2f(a2[j] * sdt[se + j]);
      v[j] = fmaf(F, S[j], v[j]);
      S[j] = fmaf(E, S[j], P);
    }
  }
#pragma unroll
  for (int j = 0; j < 8; ++j)
    state_out[((size_t)(b * DI + d0 + j)) * DS + lane] = S[j];
#pragma unroll
  for (int j = 0; j < 8; ++j)
#pragma unroll
    for (int m = 32; m; m >>= 1) v[j] += __shfl_xor(v[j], m, 64);
  if (lane == 0) {
#pragma unroll
    for (int j = 0; j < 8; ++j) {
      float s = v[j];
#pragma unroll
      for (int c = 0; c < NCH; ++c) s += accp[(b * NCH + c) * DI + d0 + j];
      accbuf[b * DI + d0 + j] = s;
    }
  }
}

// ---------------- out = ((acc + D*sxg)/S) @ W_out^T + b_out ----------------
__global__ __launch_bounds__(256) void out_gemm_k(const float* __restrict__ accb,
                                                  const float* __restrict__ sxg,
                                                  const float* __restrict__ Dv,
                                                  const float* __restrict__ W_out,
                                                  const float* __restrict__ b_out,
                                                  float* __restrict__ outpre)
{
  int b = blockIdx.y;
  int m = blockIdx.x * 8 + (threadIdx.x >> 5);
  int dl = threadIdx.x & 31;
  const float* wr = W_out + (size_t)m * DI;
  const float* ac = accb + b * DI;
  const float* sx = sxg + b * DI;
  float p = 0.f;
  for (int dd = dl; dd < DI; dd += 32) {
    float av = fmaf(Dv[dd], sx[dd], ac[dd]);
    p = fmaf(wr[dd], av, p);
  }
#pragma unroll
  for (int s = 16; s; s >>= 1) p += __shfl_xor(p, s, 32);
  if (dl == 0) outpre[b * DM + m] = p * (1.f / 2048.f) + b_out[m];
}

// ---------------- layernorm over d_model ----------------
__global__ __launch_bounds__(256) void ln_k(const float* __restrict__ outpre,
                                            const float* __restrict__ g,
                                            const float* __restrict__ bta,
                                            float* __restrict__ dout)
{
  int b = blockIdx.x;
  const float* row = outpre + b * DM;
  float s = 0.f, s2 = 0.f, vv[4];
#pragma unroll
  for (int i = 0; i < 4; i++) {
    float v = row[threadIdx.x + i * 256];
    vv[i] = v; s += v; s2 += v * v;
  }
#pragma unroll
  for (int m = 32; m; m >>= 1) { s += __shfl_xor(s, m, 64); s2 += __shfl_xor(s2, m, 64); }
  __shared__ float rs[4], rs2[4];
  int w = threadIdx.x >> 6;
  if ((threadIdx.x & 63) == 0) { rs[w] = s; rs2[w] = s2; }
  __syncthreads();
  float S = rs[0] + rs[1] + rs[2] + rs[3];
  float S2 = rs2[0] + rs2[1] + rs2[2] + rs2[3];
  float mu = S * (1.f / 1024.f);
  float var = S2 * (1.f / 1024.f) - mu * mu;
  float inv = rsqrtf(var + 1e-5f);
#pragma unroll
  for (int i = 0; i < 4; i++) {
    int c = threadIdx.x + i * 256;
    dout[b * DM + c] = (vv[i] - mu) * inv * g[c] + bta[c];
  }
}

extern "C" void kernel_launch(void* const* d_in, const int* in_sizes, int n_in,
                              void* d_out, int out_size, void* d_ws, size_t ws_size,
                              hipStream_t stream)
{
  const float* x      = (const float*)d_in[0];
  const float* state0 = (const float*)d_in[1];
  const float* W_in   = (const float*)d_in[2];
  const float* b_in   = (const float*)d_in[3];
  const float* conv_w = (const float*)d_in[4];
  const float* conv_b = (const float*)d_in[5];
  const float* W_xp   = (const float*)d_in[6];
  const float* b_xp   = (const float*)d_in[7];
  const float* W_dt   = (const float*)d_in[8];
  const float* b_dt   = (const float*)d_in[9];
  const float* A_log  = (const float*)d_in[10];
  const float* Dvec   = (const float*)d_in[11];
  const float* W_out  = (const float*)d_in[12];
  const float* b_out  = (const float*)d_in[13];
  const float* ln_g   = (const float*)d_in[14];
  const float* ln_b   = (const float*)d_in[15];
  float* out = (float*)d_out;   // [4*1024] out, then [4*2048*64] final_state

  const size_t MB = 1024 * 1024;
  char* ws = (char*)d_ws;
  unsigned short* grm  = (unsigned short*)(ws + 0);          // 32MB
  unsigned short* xcb  = (unsigned short*)(ws + 32  * MB);   // 32MB
  unsigned short* xib  = (unsigned short*)(ws + 64  * MB);   // 32MB (dead after conv)
  unsigned*       dtH  = (unsigned*)(ws + 64  * MB);         // 32MB (overlays xib)
  unsigned short* xb   = (unsigned short*)(ws + 96  * MB);   // 16MB
  unsigned short* wbin = (unsigned short*)(ws + 112 * MB);   // 8MB
  float*          xpp  = (float*)(ws + 96 * MB);             // 32MB xp partials
  unsigned*       dxg  = (unsigned*)(ws + 96  * MB);         // 64MB (overlays xpp after xpred)
  unsigned short* xpb  = (unsigned short*)(ws + 160 * MB);   // 3MB
  float*          bcI  = (float*)(ws + 163 * MB);            // 4MB
  unsigned short* wbxp = (unsigned short*)(ws + 167 * MB);   // 768KB
  unsigned short* wbdt = (unsigned short*)(ws + 167 * MB + 786432); // 256KB
  float*          sxg    = (float*)(ws + 168 * MB);                    // 32KB
  float*          sdt    = (float*)(ws + 168 * MB + 32768);            // 512KB
  float*          accb   = (float*)(ws + 168 * MB + 557056);           // 32KB
  float*          outpre = (float*)(ws + 168 * MB + 589824);           // 16KB
  float*          accp   = (float*)(ws + 168 * MB + 606208);           // 512KB
  float*          Pb   = (float*)(ws + 0);                   // 32MB (scan phase)
  float*          Fb   = (float*)(ws + 32 * MB);             // 32MB

  cvt_all_k<<<12800, 256, 0, stream>>>(x, xb, W_in, wbin, W_xp, wbxp, W_dt, wbdt);
  hipMemsetAsync(sxg, 0, 557056, stream);   // sxg + sdt
  // xz = x @ W_in^T + b_in (4-deep pipelined GEMM)
  gemm_in8_k<<<dim3(64, 32), 256, 0, stream>>>(xb, wbin, b_in, xib, grm);
  convsxg_k<<<dim3(2, 4, 128), 256, 0, stream>>>(xib, grm, conv_w, conv_b, xcb, sxg);
  gemm_bt<3><<<dim3(64, 2, 4), 256, 0, stream>>>(xcb, wbxp, nullptr, 192, 2048, 2048, 2048,
                                                 xpp, nullptr, nullptr, nullptr, 0, nullptr);
  xpred_k<<<8192, 192, 0, stream>>>(xpp, b_xp, xpb, bcI);
  gemm_bt<1><<<dim3(64, 16), 256, 0, stream>>>(xpb, wbdt, b_dt, 2048, 64, XPW, 64,
                                               dtH, dxg, xcb, grm, 0, sdt);
  scan_k<<<4096, 256, 0, stream>>>(dtH, dxg, bcI, A_log, Pb, Fb, accp);
  fixup_k<<<256, 256, 0, stream>>>(Pb, Fb, sdt, accp, A_log, state0, accb, out + 4096);
  out_gemm_k<<<dim3(128, 4), 256, 0, stream>>>(accb, sxg, Dvec, W_out, b_out, outpre);
  ln_k<<<4, 256, 0, stream>>>(outpre, ln_g, ln_b, out);
}

// Round 16
// 483.235 us; speedup vs baseline: 1.1132x; 1.1132x over previous
//
#include <hip/hip_runtime.h>
#include <hip/hip_fp16.h>

typedef __attribute__((ext_vector_type(8))) short short8;
typedef __attribute__((ext_vector_type(8))) unsigned short u16x8;
typedef __attribute__((ext_vector_type(4))) float f32x4;

#define S_LEN 2048
#define BATCH 4
#define DM 1024
#define DI 2048
#define DS 64
#define DTR 64
#define XPW 192   // dt_rank + 2*d_state
#define NCH 16    // scan chunks
#define CLEN 128  // t per chunk

typedef const __attribute__((address_space(4))) unsigned* cu_as4;

__device__ __forceinline__ unsigned short f2bf(float f){
  unsigned u = __builtin_bit_cast(unsigned, f);
  u += 0x7fffu + ((u >> 16) & 1u);
  return (unsigned short)(u >> 16);
}
__device__ __forceinline__ float bf2f(unsigned short h){
  unsigned u = ((unsigned)h) << 16;
  return __builtin_bit_cast(float, u);
}
__device__ __forceinline__ void gload16(const void* g, void* l){
  __builtin_amdgcn_global_load_lds((const __attribute__((address_space(1))) void*)g,
                                   (__attribute__((address_space(3))) void*)l, 16, 0, 0);
}
__device__ __forceinline__ float siluf_(float v){ return v / (1.f + __expf(-v)); }

// ---------------- fused f32 -> bf16 convert (4 segments) ----------------
__global__ __launch_bounds__(256) void cvt_all_k(const float* __restrict__ i0, unsigned short* __restrict__ o0,
                                                 const float* __restrict__ i1, unsigned short* __restrict__ o1,
                                                 const float* __restrict__ i2, unsigned short* __restrict__ o2,
                                                 const float* __restrict__ i3, unsigned short* __restrict__ o3)
{
  int bid = blockIdx.x;
  const float* in; unsigned short* out; int base;
  if (bid < 8192)       { in = i0; out = o0; base = bid; }
  else if (bid < 12288) { in = i1; out = o1; base = bid - 8192; }
  else if (bid < 12672) { in = i2; out = o2; base = bid - 12288; }
  else                  { in = i3; out = o3; base = bid - 12672; }
  int i = (base * 256 + threadIdx.x) * 4;
  float4 v = *(const float4*)(in + i);
  ushort4 o;
  o.x = f2bf(v.x); o.y = f2bf(v.y); o.z = f2bf(v.z); o.w = f2bf(v.w);
  *(ushort4*)(out + i) = o;
}

// ---------------- bf16 MFMA GEMM, C = A[M,K] * B[N,K]^T + bias ----------------
// EPI 1 (dt):  dt=softplus(v+2*bias); LDS-stage dt bf16; coalesced epilogue ->
//              dtH u32[b][G8][t][4] (bf16 pairs), dxg u32[b][G8][t][8], sdt atomics.
// EPI 2 (in):  cols<nsilu -> xib bf16 rm; cols>=nsilu -> grm = bf16(silu(v)) rm.
//              XCD-aware block swizzle (2048 blocks, bijective).
// EPI 3 (xp split-K): partial f32 C[kz][gr][0..255], kz = blockIdx.z, Kchunk=512.
template<int EPI>
__global__ __launch_bounds__(256)
void gemm_bt(const unsigned short* __restrict__ A, const unsigned short* __restrict__ B,
             const float* __restrict__ bias,
             int N, int K, int lda, int ldb,
             void* __restrict__ vp0, void* __restrict__ vp1,
             const void* __restrict__ vp2, const void* __restrict__ vp3,
             int nsilu, float* __restrict__ sdt)
{
  __shared__ unsigned short As[128 * 32];
  __shared__ unsigned short Bs[128 * 32];
  const int tid  = threadIdx.x;
  const int lane = tid & 63;
  const int wid  = tid >> 6;
  int bm, bn;
  if constexpr (EPI == 2) {
    int flat = blockIdx.y * 64 + blockIdx.x;
    int swz = (flat & 7) * 256 + (flat >> 3);     // XCD-contiguous
    bm = swz & 63; bn = swz >> 6;
  } else {
    bm = blockIdx.x; bn = blockIdx.y;
  }
  int k_lo = 0, k_hi = K;
  if constexpr (EPI == 3) { k_lo = blockIdx.z * 512; k_hi = k_lo + 512; }
  const int r0 = tid >> 2;           // 0..63
  const int c0 = (tid & 3) * 8;      // 0,8,16,24
  int brow0 = bn * 128 + r0;        if (brow0 > N - 1) brow0 = N - 1;
  int brow1 = bn * 128 + 64 + r0;   if (brow1 > N - 1) brow1 = N - 1;
  const unsigned short* pa0 = A + (size_t)(bm * 128 + r0) * lda + c0;
  const unsigned short* pa1 = A + (size_t)(bm * 128 + 64 + r0) * lda + c0;
  const unsigned short* pb0 = B + (size_t)brow0 * ldb + c0;
  const unsigned short* pb1 = B + (size_t)brow1 * ldb + c0;
  f32x4 acc[4][4] = {};
  const int fr = lane & 15, fq = lane >> 4;
  const int wm = (wid >> 1) * 64, wn = (wid & 1) * 64;
  const int aoff0 = (wm + fr) * 32 + fq * 8;
  const int boff0 = (wn + fr) * 32 + fq * 8;
  for (int k0 = k_lo; k0 < k_hi; k0 += 32) {
    __syncthreads();                       // prev-iter LDS reads done
    gload16(pa0 + k0, &As[tid * 8]);
    gload16(pa1 + k0, &As[2048 + tid * 8]);
    gload16(pb0 + k0, &Bs[tid * 8]);
    gload16(pb1 + k0, &Bs[2048 + tid * 8]);
    __syncthreads();                       // drains vmcnt(0): LDS ready
    short8 av[4], bv[4];
#pragma unroll
    for (int i = 0; i < 4; i++) av[i] = *(const short8*)&As[aoff0 + i * 16 * 32];
#pragma unroll
    for (int i = 0; i < 4; i++) bv[i] = *(const short8*)&Bs[boff0 + i * 16 * 32];
#pragma unroll
    for (int i = 0; i < 4; i++)
#pragma unroll
      for (int j = 0; j < 4; j++)
        acc[i][j] = __builtin_amdgcn_mfma_f32_16x16x32_bf16(av[i], bv[j], acc[i][j], 0, 0, 0);
  }

  if constexpr (EPI == 3) {
    float* xpp = (float*)vp0;     // [4][8192][256] partials
    const size_t kb = (size_t)blockIdx.z * 8192 * 256;
#pragma unroll
    for (int i = 0; i < 4; i++) {
#pragma unroll
      for (int j = 0; j < 4; j++) {
        int gc = bn * 128 + wn + j * 16 + fr;   // 0..255
#pragma unroll
        for (int e = 0; e < 4; e++) {
          int gr = bm * 128 + wm + i * 16 + fq * 4 + e;
          xpp[kb + (size_t)gr * 256 + gc] = acc[i][j][e];
        }
      }
    }
  } else if constexpr (EPI == 2) {
    unsigned short* xib = (unsigned short*)vp0;
    unsigned short* grm = (unsigned short*)vp1;
#pragma unroll
    for (int i = 0; i < 4; i++) {
#pragma unroll
      for (int j = 0; j < 4; j++) {
        int gc = bn * 128 + wn + j * 16 + fr;
        float bb = bias[gc];
#pragma unroll
        for (int e = 0; e < 4; e++) {
          int gr = bm * 128 + wm + i * 16 + fq * 4 + e;
          float v = acc[i][j][e] + bb;
          if (gc < nsilu) xib[(size_t)gr * DI + gc] = f2bf(v);
          else            grm[(size_t)gr * DI + (gc - nsilu)] = f2bf(siluf_(v));
        }
      }
    }
  } else {
    // EPI == 1: dt path; LDS-stage dt bf16, then fully coalesced global epilogue
    unsigned* dtH = (unsigned*)vp0;                    // [4][256][2048][4] u32 (bf16 pairs)
    unsigned* dxg = (unsigned*)vp1;                    // [4][256][2048][8] u32
    const unsigned short* xcb = (const unsigned short*)vp2;
    const unsigned short* grm = (const unsigned short*)vp3;
    // in-place: acc -> dt = softplus(acc + 2*b_dt)
#pragma unroll
    for (int j = 0; j < 4; j++) {
      int gc = bn * 128 + wn + j * 16 + fr;
      float bb2 = 2.f * bias[gc];
#pragma unroll
      for (int i = 0; i < 4; i++)
#pragma unroll
        for (int e = 0; e < 4; e++) {
          float v = acc[i][j][e] + bb2;
          acc[i][j][e] = fmaxf(v, 0.f) + log1pf(__expf(-fabsf(v)));
        }
    }
    __shared__ unsigned short hbuf[256 * 36];          // 18 KiB, dt bf16 (row = e*64+dl)
    const int myc = wn >> 6;                           // wave's d-chunk (0/1)
    const int tbase = wm / 4;                          // 0 or 16
    const int chk = bm >> 2;                           // scan chunk (CLEN=128 -> 4 bm per chunk)
    for (int cc = 0; cc < 2; ++cc) {
      __syncthreads();
      if (myc == cc) {
#pragma unroll
        for (int i = 0; i < 4; i++)
#pragma unroll
          for (int j = 0; j < 4; j++) {
            int dl = j * 16 + fr;                      // 0..63
            int t_ = tbase + i * 4 + fq;               // 0..31
#pragma unroll
            for (int e = 0; e < 4; e++)                // e = b index
              hbuf[(e * 64 + dl) * 36 + t_] = f2bf(acc[i][j][e]);
          }
      }
      __syncthreads();
#pragma unroll
      for (int k = 0; k < 4; ++k) {                    // dtH: 1024 tasks (e, gl8, t)
        int gidx = tid + k * 256;
        int t   = gidx & 31;
        int gl8 = (gidx >> 5) & 7;
        int e   = gidx >> 8;
        int R   = e * 64 + gl8 * 8;
        uint4 o;
        o.x = (unsigned)hbuf[(R+0)*36 + t] | ((unsigned)hbuf[(R+1)*36 + t] << 16);
        o.y = (unsigned)hbuf[(R+2)*36 + t] | ((unsigned)hbuf[(R+3)*36 + t] << 16);
        o.z = (unsigned)hbuf[(R+4)*36 + t] | ((unsigned)hbuf[(R+5)*36 + t] << 16);
        o.w = (unsigned)hbuf[(R+6)*36 + t] | ((unsigned)hbuf[(R+7)*36 + t] << 16);
        size_t G = (size_t)(bn * 16 + cc * 8 + gl8);
        *(uint4*)&dtH[(((size_t)e * 256 + G) * 2048 + bm * 32 + t) * 4] = o;
      }
      // dxg: 1024 tasks; xcb/grm read coalesced (ushort8), dt from LDS
#pragma unroll
      for (int k = 0; k < 4; ++k) {
        int gidx = tid + k * 256;
        int t   = gidx & 31;
        int gl8 = (gidx >> 5) & 7;
        int e   = gidx >> 8;
        int gr  = (bm * 32 + t) * 4 + e;
        int col = bn * 128 + cc * 64 + gl8 * 8;
        u16x8 xv = *(const u16x8*)&xcb[(size_t)gr * DI + col];
        u16x8 gv = *(const u16x8*)&grm[(size_t)gr * DI + col];
        int R = e * 64 + gl8 * 8;
        unsigned ow[8];
#pragma unroll
        for (int u = 0; u < 8; ++u) {
          float dt = bf2f(hbuf[(R + u) * 36 + t]);
          float dtx = dt * bf2f((unsigned short)xv[u]);
          ow[u] = ((unsigned)f2bf(dtx) << 16) | (unsigned)(unsigned short)gv[u];
        }
        size_t G = (size_t)(bn * 16 + cc * 8 + gl8);
        unsigned* dst = &dxg[(((size_t)e * 256 + G) * 2048 + bm * 32 + t) * 8];
        uint4 o0, o1;
        o0.x = ow[0]; o0.y = ow[1]; o0.z = ow[2]; o0.w = ow[3];
        o1.x = ow[4]; o1.y = ow[5]; o1.z = ow[6]; o1.w = ow[7];
        *(uint4*)dst = o0;
        *(uint4*)(dst + 4) = o1;
      }
      // sdt: per (e, dl) sum dt over this block's 32 t -> atomic to chunk sum
      {
        int e  = tid >> 6;
        int dl = tid & 63;
        float s = 0.f;
#pragma unroll
        for (int t = 0; t < 32; ++t)
          s += bf2f(hbuf[(e * 64 + dl) * 36 + t]);
        int g8 = bn * 16 + cc * 8 + (dl >> 3);
        atomicAdd(&sdt[(((size_t)e * NCH + chk) * 256 + g8) * 8 + (dl & 7)], s);
      }
    }
  }
}

// ------- xp split-K reduce: sum 4 partials + bias -> xpb bf16 + bcI float2 ----
__global__ __launch_bounds__(192) void xpred_k(const float* __restrict__ xpp,
                                               const float* __restrict__ bias,
                                               unsigned short* __restrict__ xpb,
                                               float* __restrict__ bcI)
{
  const int gr = blockIdx.x;         // 0..8191
  const int gc = threadIdx.x;        // 0..191
  const size_t o = (size_t)gr * 256 + gc;
  float v = xpp[o] + xpp[o + 2097152] + xpp[o + 2 * 2097152] + xpp[o + 3 * 2097152] + bias[gc];
  xpb[(size_t)gr * XPW + gc] = f2bf(v);
  if (gc >= 64 && gc < 128)      bcI[((size_t)gr * 64 + gc - 64) * 2 + 0] = v;
  else if (gc >= 128)            bcI[((size_t)gr * 64 + gc - 128) * 2 + 1] = v;
}

// ------ fused causal depthwise conv (K=4) + silu + D-term partial reduce ------
__global__ __launch_bounds__(256) void convsxg_k(const unsigned short* __restrict__ xib,
                                                 const unsigned short* __restrict__ grm,
                                                 const float* __restrict__ cw,
                                                 const float* __restrict__ cb,
                                                 unsigned short* __restrict__ xcb,
                                                 float* __restrict__ sxg)
{
  const int d4 = blockIdx.x * 1024 + threadIdx.x * 4;
  const int b  = blockIdx.y;
  const int t0 = blockIdx.z * 16;
  float4 cwv[4]; float cbv[4];
#pragma unroll
  for (int j = 0; j < 4; ++j) { cwv[j] = *(const float4*)&cw[(d4 + j) * 4]; cbv[j] = cb[d4 + j]; }
  ushort4 z4; z4.x = z4.y = z4.z = z4.w = 0;
  ushort4 xm1 = (t0 >= 1) ? *(const ushort4*)&xib[((size_t)((t0 - 1) * 4 + b)) * DI + d4] : z4;
  ushort4 xm2 = (t0 >= 2) ? *(const ushort4*)&xib[((size_t)((t0 - 2) * 4 + b)) * DI + d4] : z4;
  ushort4 xm3 = (t0 >= 3) ? *(const ushort4*)&xib[((size_t)((t0 - 3) * 4 + b)) * DI + d4] : z4;
  float sa[4] = {0.f, 0.f, 0.f, 0.f};
  for (int tt = 0; tt < 16; ++tt) {
    const int t = t0 + tt;
    const size_t row = ((size_t)(t * 4 + b)) * DI + d4;
    ushort4 x0 = *(const ushort4*)&xib[row];
    ushort4 gv = *(const ushort4*)&grm[row];
    unsigned short xr[4] = {x0.x, x0.y, x0.z, x0.w};
    unsigned short r1[4] = {xm1.x, xm1.y, xm1.z, xm1.w};
    unsigned short r2[4] = {xm2.x, xm2.y, xm2.z, xm2.w};
    unsigned short r3[4] = {xm3.x, xm3.y, xm3.z, xm3.w};
    unsigned short gg[4] = {gv.x, gv.y, gv.z, gv.w};
    unsigned short ov[4];
#pragma unroll
    for (int j = 0; j < 4; ++j) {
      float s = cbv[j];
      s = fmaf(cwv[j].w, bf2f(xr[j]), s);
      s = fmaf(cwv[j].z, bf2f(r1[j]), s);
      s = fmaf(cwv[j].y, bf2f(r2[j]), s);
      s = fmaf(cwv[j].x, bf2f(r3[j]), s);
      ov[j] = f2bf(siluf_(s));
      sa[j] = fmaf(bf2f(ov[j]), bf2f(gg[j]), sa[j]);
    }
    ushort4 o; o.x = ov[0]; o.y = ov[1]; o.z = ov[2]; o.w = ov[3];
    *(ushort4*)&xcb[row] = o;
    xm3 = xm2; xm2 = xm1; xm1 = x0;
  }
#pragma unroll
  for (int j = 0; j < 4; ++j) atomicAdd(&sxg[b * DI + d4 + j], sa[j]);
}

// ------- chunk-parallel scan: wave = (b, chunk, 8-ch group), lane = n ---------
// NCH=16 chunks of 128 t. dt stream is bf16 (SALU unpack). Emits P and F;
// E reconstructed in fixup from sdt scalar sums.
__global__ __launch_bounds__(256) void scan_k(const unsigned* __restrict__ dtHg,
                                              const unsigned* __restrict__ dxgg,
                                              const float* __restrict__ bcI,
                                              const float* __restrict__ A_log,
                                              float* __restrict__ Pb,
                                              float* __restrict__ Fb,
                                              float* __restrict__ accp)
{
  const int tid  = threadIdx.x;
  const int lane = tid & 63;
  const int gw = __builtin_amdgcn_readfirstlane(blockIdx.x * 4 + (tid >> 6));  // 0..16383
  const int b  = gw >> 12;
  const int c  = (gw >> 8) & 15;
  const int g  = gw & 255;
  const int d0 = g * 8;
  const float LOG2E = 1.4426950408889634f;
  float a2[8], st[8], Dr[8], Fr[8], acc[8];
#pragma unroll
  for (int j = 0; j < 8; ++j) {
    a2[j] = -__expf(A_log[(size_t)(d0 + j) * DS + lane]) * LOG2E;
    st[j] = 0.f; Dr[j] = 1.f; Fr[j] = 0.f; acc[j] = 0.f;
  }
  cu_as4 pdt = (cu_as4)(unsigned long long)(dtHg + (((size_t)(b * 256 + g)) * S_LEN + c * CLEN) * 4);
  cu_as4 pdx = (cu_as4)(unsigned long long)(dxgg + (((size_t)(b * 256 + g)) * S_LEN + c * CLEN) * 8);
  const float* pbc = bcI + (((size_t)(c * CLEN) * 4 + b) * 64 + lane) * 2;
#pragma unroll 4
  for (int t = 0; t < CLEN; ++t) {
    unsigned dw0 = pdt[t * 4 + 0], dw1 = pdt[t * 4 + 1];
    unsigned dw2 = pdt[t * 4 + 2], dw3 = pdt[t * 4 + 3];
    unsigned xs[8];
#pragma unroll
    for (int j = 0; j < 8; ++j) xs[j] = pdx[t * 8 + j];
    float2 bc = *(const float2*)(pbc + (size_t)t * 512);
    float dts[8];
    dts[0] = __builtin_bit_cast(float, dw0 << 16);
    dts[1] = __builtin_bit_cast(float, dw0 & 0xffff0000u);
    dts[2] = __builtin_bit_cast(float, dw1 << 16);
    dts[3] = __builtin_bit_cast(float, dw1 & 0xffff0000u);
    dts[4] = __builtin_bit_cast(float, dw2 << 16);
    dts[5] = __builtin_bit_cast(float, dw2 & 0xffff0000u);
    dts[6] = __builtin_bit_cast(float, dw3 << 16);
    dts[7] = __builtin_bit_cast(float, dw3 & 0xffff0000u);
#pragma unroll
    for (int j = 0; j < 8; ++j) {
      float dxs = __builtin_bit_cast(float, xs[j] & 0xffff0000u);
      float gsv = __builtin_bit_cast(float, xs[j] << 16);
      float dA = __builtin_amdgcn_exp2f(dts[j] * a2[j]);
      st[j] = fmaf(st[j], dA, dxs * bc.x);
      Dr[j] *= dA;
      float w = gsv * bc.y;
      acc[j] = fmaf(st[j], w, acc[j]);
      Fr[j] = fmaf(Dr[j], w, Fr[j]);
    }
  }
  const size_t sb = (((size_t)((b * NCH + c) * 256 + g)) * 8) * 64 + lane;
#pragma unroll
  for (int j = 0; j < 8; ++j) {
    Pb[sb + j * 64] = st[j];
    Fb[sb + j * 64] = Fr[j];
  }
#pragma unroll
  for (int j = 0; j < 8; ++j)
#pragma unroll
    for (int m = 32; m; m >>= 1) acc[j] += __shfl_xor(acc[j], m, 64);
  if (lane == 0) {
#pragma unroll
    for (int j = 0; j < 8; ++j)
      accp[(b * NCH + c) * DI + d0 + j] = acc[j];
  }
}

// ------- chunk chain fixup: wave = (b, 8-ch group), serial over 16 chunks -----
// E reconstructed as exp2(a2 * sdt_chunk).
__global__ __launch_bounds__(256) void fixup_k(const float* __restrict__ Pb,
                                               const float* __restrict__ Fb,
                                               const float* __restrict__ sdt,
                                               const float* __restrict__ accp,
                                               const float* __restrict__ A_log,
                                               const float* __restrict__ state_in,
                                               float* __restrict__ accbuf,
                                               float* __restrict__ state_out)
{
  const int tid  = threadIdx.x;
  const int lane = tid & 63;
  const int gw = blockIdx.x * 4 + (tid >> 6);   // 0..1023
  const int b  = gw >> 8;
  const int g  = gw & 255;
  const int d0 = g * 8;
  const float LOG2E = 1.4426950408889634f;
  float a2[8], S[8], v[8];
#pragma unroll
  for (int j = 0; j < 8; ++j) {
    a2[j] = -__expf(A_log[(size_t)(d0 + j) * DS + lane]) * LOG2E;
    S[j] = state_in[((size_t)(b * DI + d0 + j)) * DS + lane];
    v[j] = 0.f;
  }
#pragma unroll
  for (int c = 0; c < NCH; ++c) {
    const size_t sb = (((size_t)((b * NCH + c) * 256 + g)) * 8) * 64 + lane;
    const size_t se = (((size_t)(b * NCH + c)) * 256 + g) * 8;
#pragma unroll
    for (int j = 0; j < 8; ++j) {
      float P = Pb[sb + j * 64], F = Fb[sb + j * 64];
      float E = __builtin_amdgcn_exp2f(a2[j] * sdt[se + j]);
      v[j] = fmaf(F, S[j], v[j]);
      S[j] = fmaf(E, S[j], P);
    }
  }
#pragma unroll
  for (int j = 0; j < 8; ++j)
    state_out[((size_t)(b * DI + d0 + j)) * DS + lane] = S[j];
#pragma unroll
  for (int j = 0; j < 8; ++j)
#pragma unroll
    for (int m = 32; m; m >>= 1) v[j] += __shfl_xor(v[j], m, 64);
  if (lane == 0) {
#pragma unroll
    for (int j = 0; j < 8; ++j) {
      float s = v[j];
#pragma unroll
      for (int c = 0; c < NCH; ++c) s += accp[(b * NCH + c) * DI + d0 + j];
      accbuf[b * DI + d0 + j] = s;
    }
  }
}

// ---------------- out = ((acc + D*sxg)/S) @ W_out^T + b_out ----------------
__global__ __launch_bounds__(256) void out_gemm_k(const float* __restrict__ accb,
                                                  const float* __restrict__ sxg,
                                                  const float* __restrict__ Dv,
                                                  const float* __restrict__ W_out,
                                                  const float* __restrict__ b_out,
                                                  float* __restrict__ outpre)
{
  int b = blockIdx.y;
  int m = blockIdx.x * 8 + (threadIdx.x >> 5);
  int dl = threadIdx.x & 31;
  const float* wr = W_out + (size_t)m * DI;
  const float* ac = accb + b * DI;
  const float* sx = sxg + b * DI;
  float p = 0.f;
  for (int dd = dl; dd < DI; dd += 32) {
    float av = fmaf(Dv[dd], sx[dd], ac[dd]);
    p = fmaf(wr[dd], av, p);
  }
#pragma unroll
  for (int s = 16; s; s >>= 1) p += __shfl_xor(p, s, 32);
  if (dl == 0) outpre[b * DM + m] = p * (1.f / 2048.f) + b_out[m];
}

// ---------------- layernorm over d_model ----------------
__global__ __launch_bounds__(256) void ln_k(const float* __restrict__ outpre,
                                            const float* __restrict__ g,
                                            const float* __restrict__ bta,
                                            float* __restrict__ dout)
{
  int b = blockIdx.x;
  const float* row = outpre + b * DM;
  float s = 0.f, s2 = 0.f, vv[4];
#pragma unroll
  for (int i = 0; i < 4; i++) {
    float v = row[threadIdx.x + i * 256];
    vv[i] = v; s += v; s2 += v * v;
  }
#pragma unroll
  for (int m = 32; m; m >>= 1) { s += __shfl_xor(s, m, 64); s2 += __shfl_xor(s2, m, 64); }
  __shared__ float rs[4], rs2[4];
  int w = threadIdx.x >> 6;
  if ((threadIdx.x & 63) == 0) { rs[w] = s; rs2[w] = s2; }
  __syncthreads();
  float S = rs[0] + rs[1] + rs[2] + rs[3];
  float S2 = rs2[0] + rs2[1] + rs2[2] + rs2[3];
  float mu = S * (1.f / 1024.f);
  float var = S2 * (1.f / 1024.f) - mu * mu;
  float inv = rsqrtf(var + 1e-5f);
#pragma unroll
  for (int i = 0; i < 4; i++) {
    int c = threadIdx.x + i * 256;
    dout[b * DM + c] = (vv[i] - mu) * inv * g[c] + bta[c];
  }
}

extern "C" void kernel_launch(void* const* d_in, const int* in_sizes, int n_in,
                              void* d_out, int out_size, void* d_ws, size_t ws_size,
                              hipStream_t stream)
{
  const float* x      = (const float*)d_in[0];
  const float* state0 = (const float*)d_in[1];
  const float* W_in   = (const float*)d_in[2];
  const float* b_in   = (const float*)d_in[3];
  const float* conv_w = (const float*)d_in[4];
  const float* conv_b = (const float*)d_in[5];
  const float* W_xp   = (const float*)d_in[6];
  const float* b_xp   = (const float*)d_in[7];
  const float* W_dt   = (const float*)d_in[8];
  const float* b_dt   = (const float*)d_in[9];
  const float* A_log  = (const float*)d_in[10];
  const float* Dvec   = (const float*)d_in[11];
  const float* W_out  = (const float*)d_in[12];
  const float* b_out  = (const float*)d_in[13];
  const float* ln_g   = (const float*)d_in[14];
  const float* ln_b   = (const float*)d_in[15];
  float* out = (float*)d_out;   // [4*1024] out, then [4*2048*64] final_state

  const size_t MB = 1024 * 1024;
  char* ws = (char*)d_ws;
  // --- producer phase ---
  unsigned short* grm  = (unsigned short*)(ws + 0);          // 32MB gate bf16 rm (dead after dt-GEMM)
  unsigned short* xcb  = (unsigned short*)(ws + 32  * MB);   // 32MB x_conv bf16 rm (dead after dt-GEMM)
  unsigned short* xib  = (unsigned short*)(ws + 64  * MB);   // 32MB x_inner (dead after conv)
  unsigned*       dtH  = (unsigned*)(ws + 64  * MB);         // 32MB [4][256][2048][4] (overlays xib)
  unsigned short* xb   = (unsigned short*)(ws + 96  * MB);   // 16MB x bf16 (dead after gemm_in)
  unsigned short* wbin = (unsigned short*)(ws + 112 * MB);   // 8MB  W_in bf16 (dead after gemm_in)
  float*          xpp  = (float*)(ws + 96 * MB);             // 32MB [4][8192][256] xp partials
  unsigned*       dxg  = (unsigned*)(ws + 96  * MB);         // 64MB [4][256][2048][8] (overlays xpp after xpred)
  unsigned short* xpb  = (unsigned short*)(ws + 160 * MB);   // 3MB  (dead after dt-GEMM)
  float*          bcI  = (float*)(ws + 163 * MB);            // 4MB  [8192][64] float2 (read by scan)
  unsigned short* wbxp = (unsigned short*)(ws + 167 * MB);   // 768KB
  unsigned short* wbdt = (unsigned short*)(ws + 167 * MB + 786432); // 256KB
  // smalls @168MB: sxg | sdt | accb | outpre | accp
  float*          sxg    = (float*)(ws + 168 * MB);                    // 32KB [4][2048]
  float*          sdt    = (float*)(ws + 168 * MB + 32768);            // 512KB [4][16][256][8]
  float*          accb   = (float*)(ws + 168 * MB + 557056);           // 32KB
  float*          outpre = (float*)(ws + 168 * MB + 589824);           // 16KB
  float*          accp   = (float*)(ws + 168 * MB + 606208);           // 512KB [4][16][2048]
  // --- scan phase (over dead grm/xcb) ---
  float*          Pb   = (float*)(ws + 0);                   // 32MB [4][16][256][8][64]
  float*          Fb   = (float*)(ws + 32 * MB);             // 32MB

  cvt_all_k<<<12800, 256, 0, stream>>>(x, xb, W_in, wbin, W_xp, wbxp, W_dt, wbdt);
  hipMemsetAsync(sxg, 0, 557056, stream);   // sxg + sdt
  // xz = x @ W_in^T + b_in; cols<2048 -> xib bf16; cols>=2048 -> silu -> grm bf16
  gemm_bt<2><<<dim3(64, 32), 256, 0, stream>>>(xb, wbin, b_in, 4096, 1024, 1024, 1024,
                                               xib, grm, nullptr, nullptr, 2048, nullptr);
  // fused conv+silu+D-term partial
  convsxg_k<<<dim3(2, 4, 128), 256, 0, stream>>>(xib, grm, conv_w, conv_b, xcb, sxg);
  // xp = x_conv @ W_xp^T (split-K partials) -> reduce + bias -> xpb bf16 + bcI
  gemm_bt<3><<<dim3(64, 2, 4), 256, 0, stream>>>(xcb, wbxp, nullptr, 192, 2048, 2048, 2048,
                                                 xpp, nullptr, nullptr, nullptr, 0, nullptr);
  xpred_k<<<8192, 192, 0, stream>>>(xpp, b_xp, xpb, bcI);
  // dt path: softplus GEMM -> dtH (bf16) + dxg streams + sdt chunk sums
  gemm_bt<1><<<dim3(64, 16), 256, 0, stream>>>(xpb, wbdt, b_dt, 2048, 64, XPW, 64,
                                               dtH, dxg, xcb, grm, 0, sdt);
  // chunk-parallel scan (16 chunks) + serial chain fixup (E from sdt)
  scan_k<<<4096, 256, 0, stream>>>(dtH, dxg, bcI, A_log, Pb, Fb, accp);
  fixup_k<<<256, 256, 0, stream>>>(Pb, Fb, sdt, accp, A_log, state0, accb, out + 4096);
  out_gemm_k<<<dim3(128, 4), 256, 0, stream>>>(accb, sxg, Dvec, W_out, b_out, outpre);
  ln_k<<<4, 256, 0, stream>>>(outpre, ln_g, ln_b, out);
}